// Round 3
// baseline (1431.897 us; speedup 1.0000x reference)
//
#include <hip/hip_runtime.h>
#include <cstdint>

#define B 16
#define N 262144
#define PRE 6000
#define KOUT 1000
#define MW 94            // 64-bit mask words per row (6016 bits >= 6000)
#define NBIN 2049
#define IMGMAX 511.0f
#define NMS_TH 0.7f

typedef unsigned int u32;
typedef unsigned long long u64;

// ---- workspace layout (bytes) ----
#define OFF_MASK  0ull                    // 16*6000*94*8         = 72,192,000
#define OFF_SEL   72192000ull             // 16*16384*8           =  2,097,152
#define OFF_BOX   74289152ull             // 16*6016*16           =  1,540,096
#define OFF_VAL   75829248ull             // 16*96*8              =     12,288
#define OFF_HIST  75841536ull             // 16*2052*4            =    131,328
#define OFF_T     75972864ull             // 16*4                 =         64
#define OFF_CNT   75972928ull             // 16*2*4               =        128
#define WS_NEED   75973056ull

// Box decode — mirrors reference op order; contraction off so we don't fuse
// mul+add where XLA doesn't (keep/valid comparisons must match bit-for-bit).
__device__ __forceinline__ void box_from(const float4 a, const float4 d,
    float& x1, float& y1, float& x2, float& y2, bool& valid) {
#pragma clang fp contract(off)
  float w  = a.z - a.x;
  float h  = a.w - a.y;
  float cx = a.x + 0.5f * w;
  float cy = a.y + 0.5f * h;
  cx = cx + d.x * w;
  cy = cy + d.y * h;
  w = w * expf(d.z);
  h = h * expf(d.w);
  x1 = cx - 0.5f * w;
  y1 = cy - 0.5f * h;
  x2 = cx + 0.5f * w;
  y2 = cy + 0.5f * h;
  x1 = fminf(fmaxf(x1, 0.0f), IMGMAX);
  y1 = fminf(fmaxf(y1, 0.0f), IMGMAX);
  x2 = fminf(fmaxf(x2, 0.0f), IMGMAX);
  y2 = fminf(fmaxf(y2, 0.0f), IMGMAX);
  valid = ((x2 - x1) >= 16.0f) && ((y2 - y1) >= 16.0f);
}

// K1: per-image score histogram (bin 0 = invalid; bins 1..2048 = valid scores).
// Scores are uniform [0,1) -> ~128 entries/bin, so the boundary bin is small.
__global__ void k_hist(const float4* __restrict__ anch, const float2* __restrict__ probs,
                       const float4* __restrict__ delt, u32* __restrict__ hist) {
  __shared__ u32 sh[NBIN];
  int t = threadIdx.x;
  int img = blockIdx.y;
  for (int p = t; p < NBIN; p += 256) sh[p] = 0;
  __syncthreads();
  int base = blockIdx.x * 1024;
  for (int r = 0; r < 4; r++) {
    int i = base + r * 256 + t;
    float4 a = anch[i];
    float4 d = delt[(size_t)img * N + i];
    float s = probs[(size_t)img * N + i].y;
    float x1, y1, x2, y2; bool valid;
    box_from(a, d, x1, y1, x2, y2, valid);
    int bin = valid ? (1 + min(2047, (int)(s * 2048.0f))) : 0;
    atomicAdd(&sh[bin], 1u);
  }
  __syncthreads();
  for (int p = t; p < NBIN; p += 256)
    if (sh[p]) atomicAdd(&hist[img * 2052 + p], sh[p]);
}

// K2: T = max bin b (over valid bins 1..2048) with suffix_count(b) >= PRE.
// Single wave per image: 32 bins/lane in registers + shfl suffix-scan.
__global__ void k_thresh(const u32* __restrict__ hist, int* __restrict__ Tarr) {
  int img = blockIdx.x;
  int l = threadIdx.x;                       // 64 lanes
  const u32* hb = hist + img * 2052;
  u32 v[32];
  u32 csum = 0;
#pragma unroll
  for (int k = 0; k < 32; k++) { v[k] = hb[l * 32 + 1 + k]; csum += v[k]; }
  u32 sfx = csum;                            // suffix-inclusive over lanes >= l
  for (int off = 1; off < 64; off <<= 1) {
    u32 tv = __shfl_down(sfx, off);
    if (l + off < 64) sfx += tv;
  }
  u32 excl = sfx - csum;
  if (l == 0 && sfx < PRE) Tarr[img] = 0;    // degenerate: < PRE valid boxes
  if (excl < PRE && sfx >= PRE) {            // exactly one lane
    u32 acc = excl; int T = 0;
#pragma unroll
    for (int k = 31; k >= 0; k--) { acc += v[k]; if (acc >= PRE) { T = l * 32 + 1 + k; break; } }
    Tarr[img] = T;
  }
}

// K3: compact candidates, recomputing score/validity (pass-1 inputs are
// L3-resident, so this re-read is ~free and saves a 33.5 MB key array).
// key = (orderable_score << 32) | (0xFFFFFFFF - idx): descending key order ==
// descending score with ascending-index tie-break == stable argsort(-masked).
// bins > T: provably < PRE entries (list0). bin == T: boundary (list1).
__global__ void k_compact(const float4* __restrict__ anch, const float2* __restrict__ probs,
                          const float4* __restrict__ delt, const int* __restrict__ Tarr,
                          u64* __restrict__ sel, u32* __restrict__ cnt) {
  int t = threadIdx.x, img = blockIdx.y;
  int T = Tarr[img];
  int base = blockIdx.x * 1024;
  for (int r = 0; r < 4; r++) {
    int i = base + r * 256 + t;
    float4 a = anch[i];
    float4 d = delt[(size_t)img * N + i];
    float s = probs[(size_t)img * N + i].y;
    float x1, y1, x2, y2; bool valid;
    box_from(a, d, x1, y1, x2, y2, valid);
    int bin = valid ? (1 + min(2047, (int)(s * 2048.0f))) : 0;
    if (bin >= T) {
      u32 u = valid ? (__float_as_uint(s) | 0x80000000u) : 0u;
      u64 key = ((u64)u << 32) | (u64)(0xFFFFFFFFu - (u32)i);
      if (bin > T) {
        u32 pos = atomicAdd(&cnt[img * 2 + 0], 1u);
        if (pos < 8192u) sel[(size_t)img * 16384 + pos] = key;
      } else {
        u32 pos = atomicAdd(&cnt[img * 2 + 1], 1u);
        if (pos < 8192u) sel[(size_t)img * 16384 + 8192 + pos] = key;
      }
    }
  }
}

// K4: per-image bitonic sort of 8192 keys in LDS (ascending; read reversed).
// Keys are unique (idx in low bits) -> result independent of atomic order.
// Then recompute clipped boxes for sorted top-6000 and the valid bitmask.
__global__ void __launch_bounds__(1024) k_sort(const u64* __restrict__ sel,
                       const u32* __restrict__ cnt,
                       const float4* __restrict__ anch, const float4* __restrict__ delt,
                       float4* __restrict__ boxes, u64* __restrict__ validw) {
  __shared__ u64 sk[8192];  // 64 KB
  int t = threadIdx.x, img = blockIdx.x;
  u32 C1 = min(cnt[img * 2 + 0], 8192u);
  u32 nb = min(cnt[img * 2 + 1], 8192u - C1);
  u32 tot = C1 + nb;
  const u64* sb = sel + (size_t)img * 16384;
  for (int p = t; p < 8192; p += 1024) {
    u64 k = 0ull;
    if ((u32)p < C1)       k = sb[p];
    else if ((u32)p < tot) k = sb[8192 + ((u32)p - C1)];
    sk[p] = k;
  }
  __syncthreads();
  for (int k = 2; k <= 8192; k <<= 1) {
    for (int j = k >> 1; j > 0; j >>= 1) {
      for (int i = t; i < 8192; i += 1024) {
        int ixj = i ^ j;
        if (ixj > i) {
          u64 a = sk[i], b2 = sk[ixj];
          bool up = ((i & k) == 0);
          if (up ? (a > b2) : (a < b2)) { sk[i] = b2; sk[ixj] = a; }
        }
      }
      __syncthreads();
    }
  }
  // valid bitmask lives in sk[0..95] (u32[192]); disjoint from sk[8191-p], p<6000
  u32* vm = (u32*)sk;
  if (t < 192) vm[t] = 0;
  __syncthreads();
  for (int p = t; p < 6016; p += 1024) {
    float4 bx = make_float4(0.f, 0.f, 0.f, 0.f);
    if (p < PRE) {
      u64 key = sk[8191 - p];
      u32 u  = (u32)(key >> 32);
      u32 gi = 0xFFFFFFFFu - (u32)(key & 0xFFFFFFFFull);
      float4 a = anch[gi];
      float4 d = delt[(size_t)img * N + gi];
      float x1, y1, x2, y2; bool valid;
      box_from(a, d, x1, y1, x2, y2, valid);
      bx = make_float4(x1, y1, x2, y2);
      if (u != 0u) atomicOr(&vm[p >> 5], 1u << (p & 31));
    }
    boxes[(size_t)img * 6016 + p] = bx;  // rows 6000..6015 zeroed (IoU-neutral)
  }
  __syncthreads();
  if (t < 96) validw[img * 96 + t] = ((u64*)vm)[t];
}

// K5: upper-triangular IoU suppression bitmask. Block = 64 rows x 4 col-groups.
// Rows buffered in LDS so the HBM write of 64 full rows is contiguous/coalesced.
// Words below the diagonal block are zero (never written, wb pre-zeroed).
// IEEE f32 div + contract(off): bit-identical to XLA's fdiv so the >0.7
// comparison can't flip vs the reference.
__global__ void k_mask(const float4* __restrict__ boxes, u64* __restrict__ mask) {
  __shared__ u64 wb[64 * MW];        // 48,128 B
  __shared__ float4 cbox[4][64];
  __shared__ float  carea[4][64];
  int t = threadIdx.x;
  int rl = t & 63, g = t >> 6;
  int rb = blockIdx.x, img = blockIdx.y;
  const float4* bb = boxes + (size_t)img * 6016;
  int r = rb * 64 + rl;
  float4 rx = bb[r];
  float ra = (rx.z - rx.x) * (rx.w - rx.y);
  for (int p = t; p < 64 * MW; p += 256) wb[p] = 0ull;
  int jmax = (94 - rb + 3) >> 2;
  for (int j = 0; j < jmax; j++) {
    int cb = rb + g + 4 * j;
    bool act = cb < 94;
    __syncthreads();
    if (act) {
      float4 c = bb[cb * 64 + rl];
      cbox[g][rl] = c;
      carea[g][rl] = (c.z - c.x) * (c.w - c.y);
    }
    __syncthreads();
    if (act) {
#pragma clang fp contract(off)
      u64 bits = 0ull;
      for (int m = 0; m < 64; m++) {
        float4 cx = cbox[g][m];
        float xx1 = fmaxf(rx.x, cx.x);
        float yy1 = fmaxf(rx.y, cx.y);
        float xx2 = fminf(rx.z, cx.z);
        float yy2 = fminf(rx.w, cx.w);
        float inter = fmaxf(xx2 - xx1, 0.0f) * fmaxf(yy2 - yy1, 0.0f);
        float iou = inter / (ra + carea[g][m] - inter + 1e-9f);
        int c_j = cb * 64 + m;
        if (iou > NMS_TH && c_j != r) bits |= (1ull << m);
      }
      wb[rl * MW + cb] = bits;
    }
  }
  __syncthreads();
  int nrows = min(64, PRE - rb * 64);
  u64* outp = mask + ((size_t)img * PRE + (size_t)rb * 64) * MW;
  for (int p = t; p < nrows * MW; p += 256) outp[p] = wb[p];
}

// K6: sequential greedy scan, one wave per image. remv bitmask in registers
// (lane l owns words l and 64+l). Mask rows prefetched 16 deep (loads are
// row-data only, independent of the scan -> latency hidden). Early exit once
// 1000 boxes are kept (reference outputs only the first 1000 kept).
__global__ void k_scan(const u64* __restrict__ mask, const u64* __restrict__ validw,
                       const float4* __restrict__ boxes, float4* __restrict__ out) {
  __shared__ unsigned short kept[KOUT];
  int l = threadIdx.x;
  int img = blockIdx.x;
  const u64* vw = validw + img * 96;
  u64 r0 = ~vw[l];
  u64 r1 = (l < MW - 64) ? ~vw[64 + l] : ~0ull;
  const u64* mb = mask + (size_t)img * PRE * MW;

  u64 ca[16], cb[16], na[16], nb2[16];
#pragma unroll
  for (int k = 0; k < 16; k++) {
    const u64* rp = mb + (size_t)k * MW;
    ca[k] = rp[l];
    cb[k] = (l < MW - 64) ? rp[64 + l] : 0ull;
  }
  int cnt = 0; bool done = false;
  for (int base = 0; base < PRE; base += 16) {
#pragma unroll
    for (int k = 0; k < 16; k++) {
      int rr = base + 16 + k;
      if (rr < PRE) {
        const u64* rp = mb + (size_t)rr * MW;
        na[k] = rp[l];
        nb2[k] = (l < MW - 64) ? rp[64 + l] : 0ull;
      } else { na[k] = 0ull; nb2[k] = 0ull; }
    }
#pragma unroll
    for (int k = 0; k < 16; k++) {
      if (!done) {
        int i = base + k;
        int w = i >> 6;
        u64 wv = (w < 64) ? __shfl(r0, w) : __shfl(r1, w - 64);
        if (!((wv >> (i & 63)) & 1ull)) {
          if (l == 0 && cnt < KOUT) kept[cnt] = (unsigned short)i;
          cnt++;
          r0 |= ca[k];                    // words < i>>6 are zero in the row
          r1 |= cb[k];
          if (cnt >= KOUT) done = true;   // first 1000 keeps suffice
        }
      }
    }
    if (done) break;
#pragma unroll
    for (int k = 0; k < 16; k++) { ca[k] = na[k]; cb[k] = nb2[k]; }
  }
  __syncthreads();
  for (int p = l; p < KOUT; p += 64) {
    float4 v = make_float4(0.f, 0.f, 0.f, 0.f);
    if (p < cnt) v = boxes[(size_t)img * 6016 + kept[p]];
    out[(size_t)img * KOUT + p] = v;
  }
}

extern "C" void kernel_launch(void* const* d_in, const int* in_sizes, int n_in,
                              void* d_out, int out_size, void* d_ws, size_t ws_size,
                              hipStream_t stream) {
  const float4* anch  = (const float4*)d_in[0];
  const float2* probs = (const float2*)d_in[1];
  const float4* delt  = (const float4*)d_in[2];
  float4* out = (float4*)d_out;
  char* ws = (char*)d_ws;
  (void)in_sizes; (void)n_in;

  if (ws_size < WS_NEED) {  // not enough scratch: write zeros, bail cleanly
    (void)hipMemsetAsync(d_out, 0, (size_t)out_size * sizeof(float), stream);
    return;
  }

  u64* mask    = (u64*)(ws + OFF_MASK);
  u64* sel     = (u64*)(ws + OFF_SEL);
  float4* bxs  = (float4*)(ws + OFF_BOX);
  u64* validw  = (u64*)(ws + OFF_VAL);
  u32* hist    = (u32*)(ws + OFF_HIST);
  int* Tarr    = (int*)(ws + OFF_T);
  u32* cnt     = (u32*)(ws + OFF_CNT);

  // zero hist + T + counters (contiguous tail region) every call
  (void)hipMemsetAsync(ws + OFF_HIST, 0, 131520, stream);

  dim3 g1(256, B);
  k_hist<<<g1, 256, 0, stream>>>(anch, probs, delt, hist);
  k_thresh<<<B, 64, 0, stream>>>(hist, Tarr);
  k_compact<<<g1, 256, 0, stream>>>(anch, probs, delt, Tarr, sel, cnt);
  k_sort<<<B, 1024, 0, stream>>>(sel, cnt, anch, delt, bxs, validw);
  dim3 g5(94, B);
  k_mask<<<g5, 256, 0, stream>>>(bxs, mask);
  k_scan<<<B, 64, 0, stream>>>(mask, validw, bxs, out);
}

// Round 4
// 1009.018 us; speedup vs baseline: 1.4191x; 1.4191x over previous
//
#include <hip/hip_runtime.h>
#include <cstdint>

#define B 16
#define N 262144
#define PRE 6000
#define KOUT 1000
#define MW 94            // 64-bit mask words per row (6016 bits >= 6000)
#define NBIN 2049
#define IMGMAX 511.0f
#define NMS_TH 0.7f

typedef unsigned int u32;
typedef unsigned long long u64;

// ---- workspace layout (bytes) ----
#define OFF_MASK  0ull                    // 16*6000*94*8         = 72,192,000
#define OFF_SEL   72192000ull             // 16*16384*8           =  2,097,152
#define OFF_BOX   74289152ull             // 16*6016*16           =  1,540,096
#define OFF_VAL   75829248ull             // 16*96*8              =     12,288
#define OFF_HIST  75841536ull             // 16*2052*4            =    131,328
#define OFF_T     75972864ull             // 16*4                 =         64
#define OFF_CNT   75972928ull             // 16*2*4               =        128
#define WS_NEED   75973056ull

// Box decode — mirrors reference op order; contraction off so we don't fuse
// mul+add where XLA doesn't (keep/valid comparisons must match bit-for-bit).
__device__ __forceinline__ void box_from(const float4 a, const float4 d,
    float& x1, float& y1, float& x2, float& y2, bool& valid) {
#pragma clang fp contract(off)
  float w  = a.z - a.x;
  float h  = a.w - a.y;
  float cx = a.x + 0.5f * w;
  float cy = a.y + 0.5f * h;
  cx = cx + d.x * w;
  cy = cy + d.y * h;
  w = w * expf(d.z);
  h = h * expf(d.w);
  x1 = cx - 0.5f * w;
  y1 = cy - 0.5f * h;
  x2 = cx + 0.5f * w;
  y2 = cy + 0.5f * h;
  x1 = fminf(fmaxf(x1, 0.0f), IMGMAX);
  y1 = fminf(fmaxf(y1, 0.0f), IMGMAX);
  x2 = fminf(fmaxf(x2, 0.0f), IMGMAX);
  y2 = fminf(fmaxf(y2, 0.0f), IMGMAX);
  valid = ((x2 - x1) >= 16.0f) && ((y2 - y1) >= 16.0f);
}

// K1: per-image score histogram. ONE 1024-thread block per image: LDS-only
// atomics, direct final store — zero global atomics (prev version's ~800
// scattered global atomicAdds/block were the same disease as k_compact's).
__global__ void __launch_bounds__(1024) k_hist(const float4* __restrict__ anch,
                       const float2* __restrict__ probs,
                       const float4* __restrict__ delt, u32* __restrict__ hist) {
  __shared__ u32 sh[NBIN];
  int t = threadIdx.x;
  int img = blockIdx.x;
  for (int p = t; p < NBIN; p += 1024) sh[p] = 0;
  __syncthreads();
  for (int i = t; i < N; i += 1024) {
    float4 a = anch[i];
    float4 d = delt[(size_t)img * N + i];
    float s = probs[(size_t)img * N + i].y;
    float x1, y1, x2, y2; bool valid;
    box_from(a, d, x1, y1, x2, y2, valid);
    int bin = valid ? (1 + min(2047, (int)(s * 2048.0f))) : 0;
    atomicAdd(&sh[bin], 1u);
  }
  __syncthreads();
  for (int p = t; p < NBIN; p += 1024) hist[img * 2052 + p] = sh[p];
}

// K2: T = max bin b (over valid bins 1..2048) with suffix_count(b) >= PRE.
// Single wave per image: 32 bins/lane in registers + shfl suffix-scan.
__global__ void k_thresh(const u32* __restrict__ hist, int* __restrict__ Tarr) {
  int img = blockIdx.x;
  int l = threadIdx.x;                       // 64 lanes
  const u32* hb = hist + img * 2052;
  u32 v[32];
  u32 csum = 0;
#pragma unroll
  for (int k = 0; k < 32; k++) { v[k] = hb[l * 32 + 1 + k]; csum += v[k]; }
  u32 sfx = csum;                            // suffix-inclusive over lanes >= l
  for (int off = 1; off < 64; off <<= 1) {
    u32 tv = __shfl_down(sfx, off);
    if (l + off < 64) sfx += tv;
  }
  u32 excl = sfx - csum;
  if (l == 0 && sfx < PRE) Tarr[img] = 0;    // degenerate: < PRE valid boxes
  if (excl < PRE && sfx >= PRE) {            // exactly one lane
    u32 acc = excl; int T = 0;
#pragma unroll
    for (int k = 31; k >= 0; k--) { acc += v[k]; if (acc >= PRE) { T = l * 32 + 1 + k; break; } }
    Tarr[img] = T;
  }
}

// K3: compact candidates. Block-local LDS aggregation: candidates go into a
// 1024-slot LDS buffer (list0 from front, list1 from back; block handles
// exactly 1024 anchors so c0+c1 <= 1024, no overflow). ONE global atomic per
// block per list reserves a chunk of sel. Prev version did one returning
// global atomic PER CANDIDATE to 2 hot addresses/image -> ~6000-deep serial
// RMW chain @ ~95ns = the measured 579us. sel order is non-deterministic but
// keys are unique and k_sort orders them -> final output deterministic.
__global__ void k_compact(const float4* __restrict__ anch, const float2* __restrict__ probs,
                          const float4* __restrict__ delt, const int* __restrict__ Tarr,
                          u64* __restrict__ sel, u32* __restrict__ cnt) {
  __shared__ u64 buf[1024];
  __shared__ u32 c0, c1, base0, base1;
  int t = threadIdx.x, img = blockIdx.y;
  if (t == 0) { c0 = 0; c1 = 0; }
  __syncthreads();
  int T = Tarr[img];
  int base = blockIdx.x * 1024;
  for (int r = 0; r < 4; r++) {
    int i = base + r * 256 + t;
    float4 a = anch[i];
    float4 d = delt[(size_t)img * N + i];
    float s = probs[(size_t)img * N + i].y;
    float x1, y1, x2, y2; bool valid;
    box_from(a, d, x1, y1, x2, y2, valid);
    int bin = valid ? (1 + min(2047, (int)(s * 2048.0f))) : 0;
    if (bin >= T) {
      u32 u = valid ? (__float_as_uint(s) | 0x80000000u) : 0u;
      u64 key = ((u64)u << 32) | (u64)(0xFFFFFFFFu - (u32)i);
      if (bin > T) { u32 p = atomicAdd(&c0, 1u); buf[p] = key; }
      else         { u32 p = atomicAdd(&c1, 1u); buf[1023 - p] = key; }
    }
  }
  __syncthreads();
  if (t == 0 && c0) base0 = atomicAdd(&cnt[img * 2 + 0], c0);
  if (t == 1 && c1) base1 = atomicAdd(&cnt[img * 2 + 1], c1);
  __syncthreads();
  u64* sb = sel + (size_t)img * 16384;
  for (u32 p = t; p < c0; p += 256) {
    u32 dpos = base0 + p;
    if (dpos < 8192u) sb[dpos] = buf[p];
  }
  for (u32 p = t; p < c1; p += 256) {
    u32 dpos = base1 + p;
    if (dpos < 8192u) sb[8192 + dpos] = buf[1023 - p];
  }
}

// K4: per-image bitonic sort of 8192 keys in LDS (ascending; read reversed).
// Keys are unique (idx in low bits) -> result independent of atomic order.
// Then recompute clipped boxes for sorted top-6000 and the valid bitmask.
__global__ void __launch_bounds__(1024) k_sort(const u64* __restrict__ sel,
                       const u32* __restrict__ cnt,
                       const float4* __restrict__ anch, const float4* __restrict__ delt,
                       float4* __restrict__ boxes, u64* __restrict__ validw) {
  __shared__ u64 sk[8192];  // 64 KB
  int t = threadIdx.x, img = blockIdx.x;
  u32 C1 = min(cnt[img * 2 + 0], 8192u);
  u32 nb = min(cnt[img * 2 + 1], 8192u - C1);
  u32 tot = C1 + nb;
  const u64* sb = sel + (size_t)img * 16384;
  for (int p = t; p < 8192; p += 1024) {
    u64 k = 0ull;
    if ((u32)p < C1)       k = sb[p];
    else if ((u32)p < tot) k = sb[8192 + ((u32)p - C1)];
    sk[p] = k;
  }
  __syncthreads();
  for (int k = 2; k <= 8192; k <<= 1) {
    for (int j = k >> 1; j > 0; j >>= 1) {
      for (int i = t; i < 8192; i += 1024) {
        int ixj = i ^ j;
        if (ixj > i) {
          u64 a = sk[i], b2 = sk[ixj];
          bool up = ((i & k) == 0);
          if (up ? (a > b2) : (a < b2)) { sk[i] = b2; sk[ixj] = a; }
        }
      }
      __syncthreads();
    }
  }
  // valid bitmask lives in sk[0..95] (u32[192]); disjoint from sk[8191-p], p<6000
  u32* vm = (u32*)sk;
  if (t < 192) vm[t] = 0;
  __syncthreads();
  for (int p = t; p < 6016; p += 1024) {
    float4 bx = make_float4(0.f, 0.f, 0.f, 0.f);
    if (p < PRE) {
      u64 key = sk[8191 - p];
      u32 u  = (u32)(key >> 32);
      u32 gi = 0xFFFFFFFFu - (u32)(key & 0xFFFFFFFFull);
      float4 a = anch[gi];
      float4 d = delt[(size_t)img * N + gi];
      float x1, y1, x2, y2; bool valid;
      box_from(a, d, x1, y1, x2, y2, valid);
      bx = make_float4(x1, y1, x2, y2);
      if (u != 0u) atomicOr(&vm[p >> 5], 1u << (p & 31));
    }
    boxes[(size_t)img * 6016 + p] = bx;  // rows 6000..6015 zeroed (IoU-neutral)
  }
  __syncthreads();
  if (t < 96) validw[img * 96 + t] = ((u64*)vm)[t];
}

// K5: upper-triangular IoU suppression bitmask. Block = 64 rows x 4 col-groups.
// Rows buffered in LDS so the HBM write of 64 full rows is contiguous/coalesced.
// Words below the diagonal block are zero (never written, wb pre-zeroed).
// Diagonal-word bits for columns < row are set-but-harmless (matches reference:
// suppressing already-decided earlier boxes has no effect on keep[]).
__global__ void k_mask(const float4* __restrict__ boxes, u64* __restrict__ mask) {
  __shared__ u64 wb[64 * MW];        // 48,128 B
  __shared__ float4 cbox[4][64];
  __shared__ float  carea[4][64];
  int t = threadIdx.x;
  int rl = t & 63, g = t >> 6;
  int rb = blockIdx.x, img = blockIdx.y;
  const float4* bb = boxes + (size_t)img * 6016;
  int r = rb * 64 + rl;
  float4 rx = bb[r];
  float ra = (rx.z - rx.x) * (rx.w - rx.y);
  for (int p = t; p < 64 * MW; p += 256) wb[p] = 0ull;
  int jmax = (94 - rb + 3) >> 2;
  for (int j = 0; j < jmax; j++) {
    int cb = rb + g + 4 * j;
    bool act = cb < 94;
    __syncthreads();
    if (act) {
      float4 c = bb[cb * 64 + rl];
      cbox[g][rl] = c;
      carea[g][rl] = (c.z - c.x) * (c.w - c.y);
    }
    __syncthreads();
    if (act) {
#pragma clang fp contract(off)
      u64 bits = 0ull;
      for (int m = 0; m < 64; m++) {
        float4 cx = cbox[g][m];
        float xx1 = fmaxf(rx.x, cx.x);
        float yy1 = fmaxf(rx.y, cx.y);
        float xx2 = fminf(rx.z, cx.z);
        float yy2 = fminf(rx.w, cx.w);
        float inter = fmaxf(xx2 - xx1, 0.0f) * fmaxf(yy2 - yy1, 0.0f);
        float iou = inter / (ra + carea[g][m] - inter + 1e-9f);
        int c_j = cb * 64 + m;
        if (iou > NMS_TH && c_j != r) bits |= (1ull << m);
      }
      wb[rl * MW + cb] = bits;
    }
  }
  __syncthreads();
  int nrows = min(64, PRE - rb * 64);
  u64* outp = mask + ((size_t)img * PRE + (size_t)rb * 64) * MW;
  for (int p = t; p < nrows * MW; p += 256) outp[p] = wb[p];
}

// K6: sequential greedy scan, one wave per image. remv bitmask in registers
// (lane l owns words l and 64+l). Mask rows prefetched 16 deep (loads are
// row-data only, independent of the scan -> latency hidden). Early exit once
// 1000 boxes are kept (reference outputs only the first 1000 kept).
__global__ void k_scan(const u64* __restrict__ mask, const u64* __restrict__ validw,
                       const float4* __restrict__ boxes, float4* __restrict__ out) {
  __shared__ unsigned short kept[KOUT];
  int l = threadIdx.x;
  int img = blockIdx.x;
  const u64* vw = validw + img * 96;
  u64 r0 = ~vw[l];
  u64 r1 = (l < MW - 64) ? ~vw[64 + l] : ~0ull;
  const u64* mb = mask + (size_t)img * PRE * MW;

  u64 ca[16], cb[16], na[16], nb2[16];
#pragma unroll
  for (int k = 0; k < 16; k++) {
    const u64* rp = mb + (size_t)k * MW;
    ca[k] = rp[l];
    cb[k] = (l < MW - 64) ? rp[64 + l] : 0ull;
  }
  int cnt = 0; bool done = false;
  for (int base = 0; base < PRE; base += 16) {
#pragma unroll
    for (int k = 0; k < 16; k++) {
      int rr = base + 16 + k;
      if (rr < PRE) {
        const u64* rp = mb + (size_t)rr * MW;
        na[k] = rp[l];
        nb2[k] = (l < MW - 64) ? rp[64 + l] : 0ull;
      } else { na[k] = 0ull; nb2[k] = 0ull; }
    }
#pragma unroll
    for (int k = 0; k < 16; k++) {
      if (!done) {
        int i = base + k;
        int w = i >> 6;
        u64 wv = (w < 64) ? __shfl(r0, w) : __shfl(r1, w - 64);
        if (!((wv >> (i & 63)) & 1ull)) {
          if (l == 0 && cnt < KOUT) kept[cnt] = (unsigned short)i;
          cnt++;
          r0 |= ca[k];                    // words < i>>6 are zero in the row
          r1 |= cb[k];
          if (cnt >= KOUT) done = true;   // first 1000 keeps suffice
        }
      }
    }
    if (done) break;
#pragma unroll
    for (int k = 0; k < 16; k++) { ca[k] = na[k]; cb[k] = nb2[k]; }
  }
  __syncthreads();
  for (int p = l; p < KOUT; p += 64) {
    float4 v = make_float4(0.f, 0.f, 0.f, 0.f);
    if (p < cnt) v = boxes[(size_t)img * 6016 + kept[p]];
    out[(size_t)img * KOUT + p] = v;
  }
}

extern "C" void kernel_launch(void* const* d_in, const int* in_sizes, int n_in,
                              void* d_out, int out_size, void* d_ws, size_t ws_size,
                              hipStream_t stream) {
  const float4* anch  = (const float4*)d_in[0];
  const float2* probs = (const float2*)d_in[1];
  const float4* delt  = (const float4*)d_in[2];
  float4* out = (float4*)d_out;
  char* ws = (char*)d_ws;
  (void)in_sizes; (void)n_in;

  if (ws_size < WS_NEED) {  // not enough scratch: write zeros, bail cleanly
    (void)hipMemsetAsync(d_out, 0, (size_t)out_size * sizeof(float), stream);
    return;
  }

  u64* mask    = (u64*)(ws + OFF_MASK);
  u64* sel     = (u64*)(ws + OFF_SEL);
  float4* bxs  = (float4*)(ws + OFF_BOX);
  u64* validw  = (u64*)(ws + OFF_VAL);
  u32* hist    = (u32*)(ws + OFF_HIST);
  int* Tarr    = (int*)(ws + OFF_T);
  u32* cnt     = (u32*)(ws + OFF_CNT);

  // zero Tarr + cnt every call (hist is fully overwritten by k_hist now)
  (void)hipMemsetAsync(ws + OFF_T, 0, 192, stream);

  k_hist<<<B, 1024, 0, stream>>>(anch, probs, delt, hist);
  k_thresh<<<B, 64, 0, stream>>>(hist, Tarr);
  dim3 g3(256, B);
  k_compact<<<g3, 256, 0, stream>>>(anch, probs, delt, Tarr, sel, cnt);
  k_sort<<<B, 1024, 0, stream>>>(sel, cnt, anch, delt, bxs, validw);
  dim3 g5(94, B);
  k_mask<<<g5, 256, 0, stream>>>(bxs, mask);
  k_scan<<<B, 64, 0, stream>>>(mask, validw, bxs, out);
}

// Round 5
// 926.358 us; speedup vs baseline: 1.5457x; 1.0892x over previous
//
#include <hip/hip_runtime.h>
#include <cstdint>

#define B 16
#define N 262144
#define PRE 6000
#define KOUT 1000
#define MW 94            // 64-bit mask words per row (6016 bits >= 6000)
#define NBIN 2049
#define IMGMAX 511.0f
#define NMS_TH 0.7f

typedef unsigned int u32;
typedef unsigned long long u64;

// ---- workspace layout (bytes) ----
// mask is COLUMN-MAJOR: mask[img][cw][row], cw=0..93, row=0..5999.
// size = 16*94*6000*8 = 72,192,000 (same as before)
#define OFF_MASK  0ull
#define OFF_SEL   72192000ull             // 16*16384*8           =  2,097,152
#define OFF_BOX   74289152ull             // 16*6016*16           =  1,540,096
#define OFF_VAL   75829248ull             // 16*96*8              =     12,288
#define OFF_HIST  75841536ull             // 16*2052*4            =    131,328
#define OFF_T     75972864ull             // 16*4                 =         64
#define OFF_CNT   75972928ull             // 16*2*4               =        128
#define WS_NEED   75973056ull

// Box decode — mirrors reference op order; contraction off so we don't fuse
// mul+add where XLA doesn't (keep/valid comparisons must match bit-for-bit).
__device__ __forceinline__ void box_from(const float4 a, const float4 d,
    float& x1, float& y1, float& x2, float& y2, bool& valid) {
#pragma clang fp contract(off)
  float w  = a.z - a.x;
  float h  = a.w - a.y;
  float cx = a.x + 0.5f * w;
  float cy = a.y + 0.5f * h;
  cx = cx + d.x * w;
  cy = cy + d.y * h;
  w = w * expf(d.z);
  h = h * expf(d.w);
  x1 = cx - 0.5f * w;
  y1 = cy - 0.5f * h;
  x2 = cx + 0.5f * w;
  y2 = cy + 0.5f * h;
  x1 = fminf(fmaxf(x1, 0.0f), IMGMAX);
  y1 = fminf(fmaxf(y1, 0.0f), IMGMAX);
  x2 = fminf(fmaxf(x2, 0.0f), IMGMAX);
  y2 = fminf(fmaxf(y2, 0.0f), IMGMAX);
  valid = ((x2 - x1) >= 16.0f) && ((y2 - y1) >= 16.0f);
}

// K1: per-image score histogram, grid (256, B) — full-machine decode (the
// one-block-per-image variant ran on 16 of 256 CUs: ~250us of VALU on the
// 100MB decode). LDS histogram + nonzero-guarded no-return atomic merge
// (~700 nonzero bins/block, pipelined fine at L2 — R3 evidence: not in top-5).
__global__ void k_hist(const float4* __restrict__ anch, const float2* __restrict__ probs,
                       const float4* __restrict__ delt, u32* __restrict__ hist) {
  __shared__ u32 sh[NBIN];
  int t = threadIdx.x;
  int img = blockIdx.y;
  for (int p = t; p < NBIN; p += 256) sh[p] = 0;
  __syncthreads();
  int base = blockIdx.x * 1024;
  for (int r = 0; r < 4; r++) {
    int i = base + r * 256 + t;
    float4 a = anch[i];
    float4 d = delt[(size_t)img * N + i];
    float s = probs[(size_t)img * N + i].y;
    float x1, y1, x2, y2; bool valid;
    box_from(a, d, x1, y1, x2, y2, valid);
    int bin = valid ? (1 + min(2047, (int)(s * 2048.0f))) : 0;
    atomicAdd(&sh[bin], 1u);
  }
  __syncthreads();
  for (int p = t; p < NBIN; p += 256)
    if (sh[p]) atomicAdd(&hist[img * 2052 + p], sh[p]);
}

// K2: T = max bin b (over valid bins 1..2048) with suffix_count(b) >= PRE.
// Single wave per image: 32 bins/lane in registers + shfl suffix-scan.
__global__ void k_thresh(const u32* __restrict__ hist, int* __restrict__ Tarr) {
  int img = blockIdx.x;
  int l = threadIdx.x;                       // 64 lanes
  const u32* hb = hist + img * 2052;
  u32 v[32];
  u32 csum = 0;
#pragma unroll
  for (int k = 0; k < 32; k++) { v[k] = hb[l * 32 + 1 + k]; csum += v[k]; }
  u32 sfx = csum;                            // suffix-inclusive over lanes >= l
  for (int off = 1; off < 64; off <<= 1) {
    u32 tv = __shfl_down(sfx, off);
    if (l + off < 64) sfx += tv;
  }
  u32 excl = sfx - csum;
  if (l == 0 && sfx < PRE) Tarr[img] = 0;    // degenerate: < PRE valid boxes
  if (excl < PRE && sfx >= PRE) {            // exactly one lane
    u32 acc = excl; int T = 0;
#pragma unroll
    for (int k = 31; k >= 0; k--) { acc += v[k]; if (acc >= PRE) { T = l * 32 + 1 + k; break; } }
    Tarr[img] = T;
  }
}

// K3: compact candidates. Block-local LDS aggregation; ONE global atomic per
// block per list (the R3 per-candidate hot-address RMW chain was 579us).
// sel order nondeterministic; unique keys + k_sort -> deterministic output.
__global__ void k_compact(const float4* __restrict__ anch, const float2* __restrict__ probs,
                          const float4* __restrict__ delt, const int* __restrict__ Tarr,
                          u64* __restrict__ sel, u32* __restrict__ cnt) {
  __shared__ u64 buf[1024];
  __shared__ u32 c0, c1, base0, base1;
  int t = threadIdx.x, img = blockIdx.y;
  if (t == 0) { c0 = 0; c1 = 0; }
  __syncthreads();
  int T = Tarr[img];
  int base = blockIdx.x * 1024;
  for (int r = 0; r < 4; r++) {
    int i = base + r * 256 + t;
    float4 a = anch[i];
    float4 d = delt[(size_t)img * N + i];
    float s = probs[(size_t)img * N + i].y;
    float x1, y1, x2, y2; bool valid;
    box_from(a, d, x1, y1, x2, y2, valid);
    int bin = valid ? (1 + min(2047, (int)(s * 2048.0f))) : 0;
    if (bin >= T) {
      u32 u = valid ? (__float_as_uint(s) | 0x80000000u) : 0u;
      u64 key = ((u64)u << 32) | (u64)(0xFFFFFFFFu - (u32)i);
      if (bin > T) { u32 p = atomicAdd(&c0, 1u); buf[p] = key; }
      else         { u32 p = atomicAdd(&c1, 1u); buf[1023 - p] = key; }
    }
  }
  __syncthreads();
  if (t == 0 && c0) base0 = atomicAdd(&cnt[img * 2 + 0], c0);
  if (t == 1 && c1) base1 = atomicAdd(&cnt[img * 2 + 1], c1);
  __syncthreads();
  u64* sb = sel + (size_t)img * 16384;
  for (u32 p = t; p < c0; p += 256) {
    u32 dpos = base0 + p;
    if (dpos < 8192u) sb[dpos] = buf[p];
  }
  for (u32 p = t; p < c1; p += 256) {
    u32 dpos = base1 + p;
    if (dpos < 8192u) sb[8192 + dpos] = buf[1023 - p];
  }
}

// K4: per-image bitonic sort of 8192 keys in LDS (ascending; read reversed).
// Keys are unique (idx in low bits) -> result independent of atomic order.
// Then recompute clipped boxes for sorted top-6000 and the valid bitmask.
__global__ void __launch_bounds__(1024) k_sort(const u64* __restrict__ sel,
                       const u32* __restrict__ cnt,
                       const float4* __restrict__ anch, const float4* __restrict__ delt,
                       float4* __restrict__ boxes, u64* __restrict__ validw) {
  __shared__ u64 sk[8192];  // 64 KB
  int t = threadIdx.x, img = blockIdx.x;
  u32 C1 = min(cnt[img * 2 + 0], 8192u);
  u32 nb = min(cnt[img * 2 + 1], 8192u - C1);
  u32 tot = C1 + nb;
  const u64* sb = sel + (size_t)img * 16384;
  for (int p = t; p < 8192; p += 1024) {
    u64 k = 0ull;
    if ((u32)p < C1)       k = sb[p];
    else if ((u32)p < tot) k = sb[8192 + ((u32)p - C1)];
    sk[p] = k;
  }
  __syncthreads();
  for (int k = 2; k <= 8192; k <<= 1) {
    for (int j = k >> 1; j > 0; j >>= 1) {
      for (int i = t; i < 8192; i += 1024) {
        int ixj = i ^ j;
        if (ixj > i) {
          u64 a = sk[i], b2 = sk[ixj];
          bool up = ((i & k) == 0);
          if (up ? (a > b2) : (a < b2)) { sk[i] = b2; sk[ixj] = a; }
        }
      }
      __syncthreads();
    }
  }
  // valid bitmask lives in sk[0..95] (u32[192]); disjoint from sk[8191-p], p<6000
  u32* vm = (u32*)sk;
  if (t < 192) vm[t] = 0;
  __syncthreads();
  for (int p = t; p < 6016; p += 1024) {
    float4 bx = make_float4(0.f, 0.f, 0.f, 0.f);
    if (p < PRE) {
      u64 key = sk[8191 - p];
      u32 u  = (u32)(key >> 32);
      u32 gi = 0xFFFFFFFFu - (u32)(key & 0xFFFFFFFFull);
      float4 a = anch[gi];
      float4 d = delt[(size_t)img * N + gi];
      float x1, y1, x2, y2; bool valid;
      box_from(a, d, x1, y1, x2, y2, valid);
      bx = make_float4(x1, y1, x2, y2);
      if (u != 0u) atomicOr(&vm[p >> 5], 1u << (p & 31));
    }
    boxes[(size_t)img * 6016 + p] = bx;  // rows 6000..6015 zeroed (IoU-neutral)
  }
  __syncthreads();
  if (t < 96) validw[img * 96 + t] = ((u64*)vm)[t];
}

// K5: upper-triangular IoU suppression bitmask, COLUMN-MAJOR output
// mask[img][cw][row]: a wave (fixed cw, rows rb*64+rl) stores 64 consecutive
// u64 = one coalesced 512B store — no LDS row-buffer needed. LDS drops
// 53KB -> 5KB: occupancy was the 400us bottleneck (20.5% occ, 66% VALUBusy).
// Only upper-triangle words (cw >= rb) are written; k_scan guards the rest.
__global__ void k_mask(const float4* __restrict__ boxes, u64* __restrict__ mask) {
  __shared__ float4 cbox[4][64];
  __shared__ float  carea[4][64];
  int t = threadIdx.x;
  int rl = t & 63, g = t >> 6;
  int rb = blockIdx.x, img = blockIdx.y;
  const float4* bb = boxes + (size_t)img * 6016;
  int r = rb * 64 + rl;
  float4 rx = bb[r];
  float ra = (rx.z - rx.x) * (rx.w - rx.y);
  u64* mimg = mask + (size_t)img * 94 * 6000;
  int jmax = (94 - rb + 3) >> 2;
  for (int j = 0; j < jmax; j++) {
    int cb = rb + g + 4 * j;
    bool act = cb < 94;
    __syncthreads();
    if (act) {
      float4 c = bb[cb * 64 + rl];
      cbox[g][rl] = c;
      carea[g][rl] = (c.z - c.x) * (c.w - c.y);
    }
    __syncthreads();
    if (act) {
#pragma clang fp contract(off)
      u64 bits = 0ull;
      for (int m = 0; m < 64; m++) {
        float4 cx = cbox[g][m];
        float xx1 = fmaxf(rx.x, cx.x);
        float yy1 = fmaxf(rx.y, cx.y);
        float xx2 = fminf(rx.z, cx.z);
        float yy2 = fminf(rx.w, cx.w);
        float inter = fmaxf(xx2 - xx1, 0.0f) * fmaxf(yy2 - yy1, 0.0f);
        float iou = inter / (ra + carea[g][m] - inter + 1e-9f);
        int c_j = cb * 64 + m;
        if (iou > NMS_TH && c_j != r) bits |= (1ull << m);
      }
      if (r < PRE) mimg[(size_t)cb * 6000 + r] = bits;
    }
  }
}

// K6: sequential greedy scan, one wave per image. remv bitmask in registers
// (lane l owns words l and 64+l). Column-major mask: lane l's data for rows
// base..base+15 is 16 CONSECUTIVE u64 (128B contiguous per lane). Words below
// the diagonal are unwritten garbage -> (l >= w) guards on the OR. Early exit
// once 1000 kept (reference outputs only the first 1000 kept).
__global__ void k_scan(const u64* __restrict__ mask, const u64* __restrict__ validw,
                       const float4* __restrict__ boxes, float4* __restrict__ out) {
  __shared__ unsigned short kept[KOUT];
  int l = threadIdx.x;
  int img = blockIdx.x;
  const u64* vw = validw + img * 96;
  u64 r0 = ~vw[l];
  u64 r1 = (l < MW - 64) ? ~vw[64 + l] : ~0ull;
  const u64* c0p = mask + ((size_t)img * 94 + l) * 6000;
  const u64* c1p = mask + ((size_t)img * 94 + (l < MW - 64 ? 64 + l : 0)) * 6000;

  u64 ca[16], cb[16], na[16], nb2[16];
#pragma unroll
  for (int k = 0; k < 16; k++) {
    ca[k] = c0p[k];
    cb[k] = (l < MW - 64) ? c1p[k] : 0ull;
  }
  int cnt = 0; bool done = false;
  for (int base = 0; base < PRE; base += 16) {
#pragma unroll
    for (int k = 0; k < 16; k++) {
      int rr = base + 16 + k;
      if (rr < PRE) {
        na[k]  = c0p[rr];
        nb2[k] = (l < MW - 64) ? c1p[rr] : 0ull;
      } else { na[k] = 0ull; nb2[k] = 0ull; }
    }
#pragma unroll
    for (int k = 0; k < 16; k++) {
      if (!done) {
        int i = base + k;
        int w = i >> 6;
        u64 wv = (w < 64) ? __shfl(r0, w) : __shfl(r1, w - 64);
        if (!((wv >> (i & 63)) & 1ull)) {
          if (l == 0 && cnt < KOUT) kept[cnt] = (unsigned short)i;
          cnt++;
          r0 |= (l >= w)        ? ca[k] : 0ull;   // words < w are unwritten junk
          r1 |= ((64 + l) >= w) ? cb[k] : 0ull;
          if (cnt >= KOUT) done = true;           // first 1000 keeps suffice
        }
      }
    }
    if (done) break;
#pragma unroll
    for (int k = 0; k < 16; k++) { ca[k] = na[k]; cb[k] = nb2[k]; }
  }
  __syncthreads();
  for (int p = l; p < KOUT; p += 64) {
    float4 v = make_float4(0.f, 0.f, 0.f, 0.f);
    if (p < cnt) v = boxes[(size_t)img * 6016 + kept[p]];
    out[(size_t)img * KOUT + p] = v;
  }
}

extern "C" void kernel_launch(void* const* d_in, const int* in_sizes, int n_in,
                              void* d_out, int out_size, void* d_ws, size_t ws_size,
                              hipStream_t stream) {
  const float4* anch  = (const float4*)d_in[0];
  const float2* probs = (const float2*)d_in[1];
  const float4* delt  = (const float4*)d_in[2];
  float4* out = (float4*)d_out;
  char* ws = (char*)d_ws;
  (void)in_sizes; (void)n_in;

  if (ws_size < WS_NEED) {  // not enough scratch: write zeros, bail cleanly
    (void)hipMemsetAsync(d_out, 0, (size_t)out_size * sizeof(float), stream);
    return;
  }

  u64* mask    = (u64*)(ws + OFF_MASK);
  u64* sel     = (u64*)(ws + OFF_SEL);
  float4* bxs  = (float4*)(ws + OFF_BOX);
  u64* validw  = (u64*)(ws + OFF_VAL);
  u32* hist    = (u32*)(ws + OFF_HIST);
  int* Tarr    = (int*)(ws + OFF_T);
  u32* cnt     = (u32*)(ws + OFF_CNT);

  // zero hist + Tarr + cnt every call (contiguous tail region)
  (void)hipMemsetAsync(ws + OFF_HIST, 0, 131520, stream);

  dim3 g1(256, B);
  k_hist<<<g1, 256, 0, stream>>>(anch, probs, delt, hist);
  k_thresh<<<B, 64, 0, stream>>>(hist, Tarr);
  k_compact<<<g1, 256, 0, stream>>>(anch, probs, delt, Tarr, sel, cnt);
  k_sort<<<B, 1024, 0, stream>>>(sel, cnt, anch, delt, bxs, validw);
  dim3 g5(94, B);
  k_mask<<<g5, 256, 0, stream>>>(bxs, mask);
  k_scan<<<B, 64, 0, stream>>>(mask, validw, bxs, out);
}

// Round 6
// 503.381 us; speedup vs baseline: 2.8446x; 1.8403x over previous
//
#include <hip/hip_runtime.h>
#include <cstdint>

#define B 16
#define N 262144
#define PRE 6000
#define KOUT 1000
#define MW 94            // 64-bit mask words per row (6016 bits >= 6000)
#define CW 40            // fast-path column words: rows 0..2559 (see k_scan_fast)
#define NBIN 2049
#define IMGMAX 511.0f
#define NMS_TH 0.7f

typedef unsigned int u32;
typedef unsigned long long u64;

// ---- workspace layout (bytes) ----
// mask is COLUMN-MAJOR: mask[img][cw][row], cw=0..93, row=0..5999.
#define OFF_MASK  0ull                    // 16*94*6000*8         = 72,192,000
#define OFF_SEL   72192000ull             // 16*16384*8           =  2,097,152
#define OFF_BOX   74289152ull             // 16*6016*16           =  1,540,096
#define OFF_VAL   75829248ull             // 16*96*8              =     12,288
#define OFF_HIST  75841536ull             // 16*2052*4            =    131,328
#define OFF_T     75972864ull             // 16*4                 =         64
#define OFF_CNT   75972928ull             // 16*2*4               =        128
#define OFF_FLAG  75973056ull             // 16*4                 =         64
#define WS_NEED   75973120ull

// Box decode — mirrors reference op order; contraction off so we don't fuse
// mul+add where XLA doesn't (keep/valid comparisons must match bit-for-bit).
__device__ __forceinline__ void box_from(const float4 a, const float4 d,
    float& x1, float& y1, float& x2, float& y2, bool& valid) {
#pragma clang fp contract(off)
  float w  = a.z - a.x;
  float h  = a.w - a.y;
  float cx = a.x + 0.5f * w;
  float cy = a.y + 0.5f * h;
  cx = cx + d.x * w;
  cy = cy + d.y * h;
  w = w * expf(d.z);
  h = h * expf(d.w);
  x1 = cx - 0.5f * w;
  y1 = cy - 0.5f * h;
  x2 = cx + 0.5f * w;
  y2 = cy + 0.5f * h;
  x1 = fminf(fmaxf(x1, 0.0f), IMGMAX);
  y1 = fminf(fmaxf(y1, 0.0f), IMGMAX);
  x2 = fminf(fmaxf(x2, 0.0f), IMGMAX);
  y2 = fminf(fmaxf(y2, 0.0f), IMGMAX);
  valid = ((x2 - x1) >= 16.0f) && ((y2 - y1) >= 16.0f);
}

// IoU > 0.7 decision, bit-exact vs IEEE div: fast path uses v_rcp (<=2ulp);
// only lanes with |qa-0.7| <= 1e-4 (P ~ 1e-5) take the exact-div path under
// exec mask. rcp error near 0.7 is ~2e-7 — 500x inside the guard.
__device__ __forceinline__ bool iou_gt(float inter, float denom) {
  float qa = inter * __builtin_amdgcn_rcpf(denom);
  if (__builtin_expect(fabsf(qa - NMS_TH) <= 1e-4f, 0))
    return (inter / denom) > NMS_TH;
  return qa > NMS_TH;
}

// K1: per-image score histogram, grid (256, B) — full-machine decode.
// LDS histogram + nonzero-guarded no-return atomic merge.
__global__ void k_hist(const float4* __restrict__ anch, const float2* __restrict__ probs,
                       const float4* __restrict__ delt, u32* __restrict__ hist) {
  __shared__ u32 sh[NBIN];
  int t = threadIdx.x;
  int img = blockIdx.y;
  for (int p = t; p < NBIN; p += 256) sh[p] = 0;
  __syncthreads();
  int base = blockIdx.x * 1024;
  for (int r = 0; r < 4; r++) {
    int i = base + r * 256 + t;
    float4 a = anch[i];
    float4 d = delt[(size_t)img * N + i];
    float s = probs[(size_t)img * N + i].y;
    float x1, y1, x2, y2; bool valid;
    box_from(a, d, x1, y1, x2, y2, valid);
    int bin = valid ? (1 + min(2047, (int)(s * 2048.0f))) : 0;
    atomicAdd(&sh[bin], 1u);
  }
  __syncthreads();
  for (int p = t; p < NBIN; p += 256)
    if (sh[p]) atomicAdd(&hist[img * 2052 + p], sh[p]);
}

// K2: T = max bin b (over valid bins 1..2048) with suffix_count(b) >= PRE.
__global__ void k_thresh(const u32* __restrict__ hist, int* __restrict__ Tarr) {
  int img = blockIdx.x;
  int l = threadIdx.x;                       // 64 lanes
  const u32* hb = hist + img * 2052;
  u32 v[32];
  u32 csum = 0;
#pragma unroll
  for (int k = 0; k < 32; k++) { v[k] = hb[l * 32 + 1 + k]; csum += v[k]; }
  u32 sfx = csum;                            // suffix-inclusive over lanes >= l
  for (int off = 1; off < 64; off <<= 1) {
    u32 tv = __shfl_down(sfx, off);
    if (l + off < 64) sfx += tv;
  }
  u32 excl = sfx - csum;
  if (l == 0 && sfx < PRE) Tarr[img] = 0;    // degenerate: < PRE valid boxes
  if (excl < PRE && sfx >= PRE) {            // exactly one lane
    u32 acc = excl; int T = 0;
#pragma unroll
    for (int k = 31; k >= 0; k--) { acc += v[k]; if (acc >= PRE) { T = l * 32 + 1 + k; break; } }
    Tarr[img] = T;
  }
}

// K3: compact candidates. Block-local LDS aggregation; ONE global atomic per
// block per list. sel order nondeterministic; unique keys + k_sort -> det.
__global__ void k_compact(const float4* __restrict__ anch, const float2* __restrict__ probs,
                          const float4* __restrict__ delt, const int* __restrict__ Tarr,
                          u64* __restrict__ sel, u32* __restrict__ cnt) {
  __shared__ u64 buf[1024];
  __shared__ u32 c0, c1, base0, base1;
  int t = threadIdx.x, img = blockIdx.y;
  if (t == 0) { c0 = 0; c1 = 0; }
  __syncthreads();
  int T = Tarr[img];
  int base = blockIdx.x * 1024;
  for (int r = 0; r < 4; r++) {
    int i = base + r * 256 + t;
    float4 a = anch[i];
    float4 d = delt[(size_t)img * N + i];
    float s = probs[(size_t)img * N + i].y;
    float x1, y1, x2, y2; bool valid;
    box_from(a, d, x1, y1, x2, y2, valid);
    int bin = valid ? (1 + min(2047, (int)(s * 2048.0f))) : 0;
    if (bin >= T) {
      u32 u = valid ? (__float_as_uint(s) | 0x80000000u) : 0u;
      u64 key = ((u64)u << 32) | (u64)(0xFFFFFFFFu - (u32)i);
      if (bin > T) { u32 p = atomicAdd(&c0, 1u); buf[p] = key; }
      else         { u32 p = atomicAdd(&c1, 1u); buf[1023 - p] = key; }
    }
  }
  __syncthreads();
  if (t == 0 && c0) base0 = atomicAdd(&cnt[img * 2 + 0], c0);
  if (t == 1 && c1) base1 = atomicAdd(&cnt[img * 2 + 1], c1);
  __syncthreads();
  u64* sb = sel + (size_t)img * 16384;
  for (u32 p = t; p < c0; p += 256) {
    u32 dpos = base0 + p;
    if (dpos < 8192u) sb[dpos] = buf[p];
  }
  for (u32 p = t; p < c1; p += 256) {
    u32 dpos = base1 + p;
    if (dpos < 8192u) sb[8192 + dpos] = buf[1023 - p];
  }
}

// K4: per-image bitonic sort of 8192 keys in LDS (ascending; read reversed).
__global__ void __launch_bounds__(1024) k_sort(const u64* __restrict__ sel,
                       const u32* __restrict__ cnt,
                       const float4* __restrict__ anch, const float4* __restrict__ delt,
                       float4* __restrict__ boxes, u64* __restrict__ validw) {
  __shared__ u64 sk[8192];  // 64 KB
  int t = threadIdx.x, img = blockIdx.x;
  u32 C1 = min(cnt[img * 2 + 0], 8192u);
  u32 nb = min(cnt[img * 2 + 1], 8192u - C1);
  u32 tot = C1 + nb;
  const u64* sb = sel + (size_t)img * 16384;
  for (int p = t; p < 8192; p += 1024) {
    u64 k = 0ull;
    if ((u32)p < C1)       k = sb[p];
    else if ((u32)p < tot) k = sb[8192 + ((u32)p - C1)];
    sk[p] = k;
  }
  __syncthreads();
  for (int k = 2; k <= 8192; k <<= 1) {
    for (int j = k >> 1; j > 0; j >>= 1) {
      for (int i = t; i < 8192; i += 1024) {
        int ixj = i ^ j;
        if (ixj > i) {
          u64 a = sk[i], b2 = sk[ixj];
          bool up = ((i & k) == 0);
          if (up ? (a > b2) : (a < b2)) { sk[i] = b2; sk[ixj] = a; }
        }
      }
      __syncthreads();
    }
  }
  // valid bitmask lives in sk[0..95] (u32[192]); disjoint from sk[8191-p], p<6000
  u32* vm = (u32*)sk;
  if (t < 192) vm[t] = 0;
  __syncthreads();
  for (int p = t; p < 6016; p += 1024) {
    float4 bx = make_float4(0.f, 0.f, 0.f, 0.f);
    if (p < PRE) {
      u64 key = sk[8191 - p];
      u32 u  = (u32)(key >> 32);
      u32 gi = 0xFFFFFFFFu - (u32)(key & 0xFFFFFFFFull);
      float4 a = anch[gi];
      float4 d = delt[(size_t)img * N + gi];
      float x1, y1, x2, y2; bool valid;
      box_from(a, d, x1, y1, x2, y2, valid);
      bx = make_float4(x1, y1, x2, y2);
      if (u != 0u) atomicOr(&vm[p >> 5], 1u << (p & 31));
    }
    boxes[(size_t)img * 6016 + p] = bx;  // rows 6000..6015 zeroed (IoU-neutral)
  }
  __syncthreads();
  if (t < 96) validw[img * 96 + t] = ((u64*)vm)[t];
}

// K5a: IoU suppression bitmask, FAST REGION ONLY: column words 0..CW-1 with
// their upper-triangle row blocks (rows < CW*64). 820 of 4465 block-tiles =
// 18% of the full triangle. k_scan only reads column words <= R/64 where R is
// the row of the 1000th keep (expected ~1500-1800 << CW*64=2560).
// COLUMN-MAJOR store: wave (fixed cb, 64 rows) = one coalesced 512B store.
__global__ void k_mask(const float4* __restrict__ boxes, u64* __restrict__ mask) {
  __shared__ float4 cbox[4][64];
  __shared__ float  carea[4][64];
  int t = threadIdx.x;
  int rl = t & 63, g = t >> 6;
  int rb = blockIdx.x, img = blockIdx.y;     // rb in [0, CW)
  const float4* bb = boxes + (size_t)img * 6016;
  int r = rb * 64 + rl;
  float4 rx = bb[r];
  float ra = (rx.z - rx.x) * (rx.w - rx.y);
  u64* mimg = mask + (size_t)img * 94 * 6000;
  int jmax = (CW - rb + 3) >> 2;
  for (int j = 0; j < jmax; j++) {
    int cb = rb + g + 4 * j;
    bool act = cb < CW;
    __syncthreads();
    if (act) {
      float4 c = bb[cb * 64 + rl];
      cbox[g][rl] = c;
      carea[g][rl] = (c.z - c.x) * (c.w - c.y);
    }
    __syncthreads();
    if (act) {
#pragma clang fp contract(off)
      u64 bits = 0ull;
      for (int m = 0; m < 64; m++) {
        float4 cx = cbox[g][m];
        float xx1 = fmaxf(rx.x, cx.x);
        float yy1 = fmaxf(rx.y, cx.y);
        float xx2 = fminf(rx.z, cx.z);
        float yy2 = fminf(rx.w, cx.w);
        float inter = fmaxf(xx2 - xx1, 0.0f) * fmaxf(yy2 - yy1, 0.0f);
        float denom = ra + carea[g][m] - inter + 1e-9f;
        int c_j = cb * 64 + m;
        if (iou_gt(inter, denom) && c_j != r) bits |= (1ull << m);
      }
      mimg[(size_t)cb * 6000 + r] = bits;
    }
  }
}

// K5b: rescue — remaining triangle (cb >= max(rb,CW)). No-op when the fast
// scan succeeded for this image (okf[img]==1, the expected case).
__global__ void k_mask_rest(const float4* __restrict__ boxes, u64* __restrict__ mask,
                            const u32* __restrict__ okf) {
  int rb = blockIdx.x, img = blockIdx.y;
  if (okf[img]) return;
  __shared__ float4 cbox[4][64];
  __shared__ float  carea[4][64];
  int t = threadIdx.x;
  int rl = t & 63, g = t >> 6;
  const float4* bb = boxes + (size_t)img * 6016;
  int r = rb * 64 + rl;
  float4 rx = bb[r];
  float ra = (rx.z - rx.x) * (rx.w - rx.y);
  u64* mimg = mask + (size_t)img * 94 * 6000;
  int cb0 = rb > CW ? rb : CW;
  int jmax = (94 - cb0 + 3) >> 2;
  for (int j = 0; j < jmax; j++) {
    int cb = cb0 + g + 4 * j;
    bool act = cb < 94;
    __syncthreads();
    if (act) {
      float4 c = bb[cb * 64 + rl];
      cbox[g][rl] = c;
      carea[g][rl] = (c.z - c.x) * (c.w - c.y);
    }
    __syncthreads();
    if (act) {
#pragma clang fp contract(off)
      u64 bits = 0ull;
      for (int m = 0; m < 64; m++) {
        float4 cx = cbox[g][m];
        float xx1 = fmaxf(rx.x, cx.x);
        float yy1 = fmaxf(rx.y, cx.y);
        float xx2 = fminf(rx.z, cx.z);
        float yy2 = fminf(rx.w, cx.w);
        float inter = fmaxf(xx2 - xx1, 0.0f) * fmaxf(yy2 - yy1, 0.0f);
        float denom = ra + carea[g][m] - inter + 1e-9f;
        int c_j = cb * 64 + m;
        if (iou_gt(inter, denom) && c_j != r) bits |= (1ull << m);
      }
      if (r < PRE) mimg[(size_t)cb * 6000 + r] = bits;
    }
  }
}

// K6a: fast greedy scan over rows 0..CW*64-1, one wave per image. Lane l<CW
// owns column word l (16 consecutive u64 per prefetch step — column-major).
// Succeeds iff 1000 keeps found within CW*64 rows; writes okf + output then.
__global__ void k_scan_fast(const u64* __restrict__ mask, const u64* __restrict__ validw,
                            const float4* __restrict__ boxes, float4* __restrict__ out,
                            u32* __restrict__ okf) {
  __shared__ unsigned short kept[KOUT];
  int l = threadIdx.x;
  int img = blockIdx.x;
  const u64* vw = validw + img * 96;
  u64 r0 = ~vw[l];                            // lanes >= CW never consulted (w<CW)
  const u64* c0p = mask + ((size_t)img * 94 + l) * 6000;
  bool ld = (l < CW);

  u64 ca[16], na[16];
#pragma unroll
  for (int k = 0; k < 16; k++) ca[k] = ld ? c0p[k] : 0ull;
  int cnt = 0; bool done = false;
  for (int base = 0; base < CW * 64; base += 16) {
#pragma unroll
    for (int k = 0; k < 16; k++) {
      int rr = base + 16 + k;
      na[k] = (ld && rr < CW * 64) ? c0p[rr] : 0ull;
    }
#pragma unroll
    for (int k = 0; k < 16; k++) {
      if (!done) {
        int i = base + k;
        int w = i >> 6;
        u64 wv = __shfl(r0, w);
        if (!((wv >> (i & 63)) & 1ull)) {
          if (l == 0 && cnt < KOUT) kept[cnt] = (unsigned short)i;
          cnt++;
          r0 |= (l >= w) ? ca[k] : 0ull;      // words < w unwritten junk
          if (cnt >= KOUT) done = true;
        }
      }
    }
    if (done) break;
#pragma unroll
    for (int k = 0; k < 16; k++) ca[k] = na[k];
  }
  if (l == 0) okf[img] = (cnt >= KOUT) ? 1u : 0u;
  __syncthreads();
  if (cnt >= KOUT) {
    for (int p = l; p < KOUT; p += 64)
      out[(size_t)img * KOUT + p] = boxes[(size_t)img * 6016 + kept[p]];
  }
}

// K6b: full-depth rescue scan (94 words, rows 0..5999). No-op when fast
// scan succeeded. Identical semantics to the reference NMS.
__global__ void k_scan_full(const u64* __restrict__ mask, const u64* __restrict__ validw,
                            const float4* __restrict__ boxes, float4* __restrict__ out,
                            const u32* __restrict__ okf) {
  int img = blockIdx.x;
  if (okf[img]) return;
  __shared__ unsigned short kept[KOUT];
  int l = threadIdx.x;
  const u64* vw = validw + img * 96;
  u64 r0 = ~vw[l];
  u64 r1 = (l < MW - 64) ? ~vw[64 + l] : ~0ull;
  const u64* c0p = mask + ((size_t)img * 94 + l) * 6000;
  const u64* c1p = mask + ((size_t)img * 94 + (l < MW - 64 ? 64 + l : 0)) * 6000;

  u64 ca[16], cb[16], na[16], nb2[16];
#pragma unroll
  for (int k = 0; k < 16; k++) {
    ca[k] = c0p[k];
    cb[k] = (l < MW - 64) ? c1p[k] : 0ull;
  }
  int cnt = 0; bool done = false;
  for (int base = 0; base < PRE; base += 16) {
#pragma unroll
    for (int k = 0; k < 16; k++) {
      int rr = base + 16 + k;
      if (rr < PRE) {
        na[k]  = c0p[rr];
        nb2[k] = (l < MW - 64) ? c1p[rr] : 0ull;
      } else { na[k] = 0ull; nb2[k] = 0ull; }
    }
#pragma unroll
    for (int k = 0; k < 16; k++) {
      if (!done) {
        int i = base + k;
        int w = i >> 6;
        u64 wv = (w < 64) ? __shfl(r0, w) : __shfl(r1, w - 64);
        if (!((wv >> (i & 63)) & 1ull)) {
          if (l == 0 && cnt < KOUT) kept[cnt] = (unsigned short)i;
          cnt++;
          r0 |= (l >= w)        ? ca[k] : 0ull;
          r1 |= ((64 + l) >= w) ? cb[k] : 0ull;
          if (cnt >= KOUT) done = true;
        }
      }
    }
    if (done) break;
#pragma unroll
    for (int k = 0; k < 16; k++) { ca[k] = na[k]; cb[k] = nb2[k]; }
  }
  __syncthreads();
  for (int p = l; p < KOUT; p += 64) {
    float4 v = make_float4(0.f, 0.f, 0.f, 0.f);
    if (p < cnt) v = boxes[(size_t)img * 6016 + kept[p]];
    out[(size_t)img * KOUT + p] = v;
  }
}

extern "C" void kernel_launch(void* const* d_in, const int* in_sizes, int n_in,
                              void* d_out, int out_size, void* d_ws, size_t ws_size,
                              hipStream_t stream) {
  const float4* anch  = (const float4*)d_in[0];
  const float2* probs = (const float2*)d_in[1];
  const float4* delt  = (const float4*)d_in[2];
  float4* out = (float4*)d_out;
  char* ws = (char*)d_ws;
  (void)in_sizes; (void)n_in;

  if (ws_size < WS_NEED) {  // not enough scratch: write zeros, bail cleanly
    (void)hipMemsetAsync(d_out, 0, (size_t)out_size * sizeof(float), stream);
    return;
  }

  u64* mask    = (u64*)(ws + OFF_MASK);
  u64* sel     = (u64*)(ws + OFF_SEL);
  float4* bxs  = (float4*)(ws + OFF_BOX);
  u64* validw  = (u64*)(ws + OFF_VAL);
  u32* hist    = (u32*)(ws + OFF_HIST);
  int* Tarr    = (int*)(ws + OFF_T);
  u32* cnt     = (u32*)(ws + OFF_CNT);
  u32* okf     = (u32*)(ws + OFF_FLAG);

  // zero hist + Tarr + cnt every call (contiguous tail region)
  (void)hipMemsetAsync(ws + OFF_HIST, 0, 131520, stream);

  dim3 g1(256, B);
  k_hist<<<g1, 256, 0, stream>>>(anch, probs, delt, hist);
  k_thresh<<<B, 64, 0, stream>>>(hist, Tarr);
  k_compact<<<g1, 256, 0, stream>>>(anch, probs, delt, Tarr, sel, cnt);
  k_sort<<<B, 1024, 0, stream>>>(sel, cnt, anch, delt, bxs, validw);
  dim3 g5(CW, B);
  k_mask<<<g5, 256, 0, stream>>>(bxs, mask);
  k_scan_fast<<<B, 64, 0, stream>>>(mask, validw, bxs, out, okf);
  dim3 g5b(94, B);
  k_mask_rest<<<g5b, 256, 0, stream>>>(bxs, mask, okf);
  k_scan_full<<<B, 64, 0, stream>>>(mask, validw, bxs, out, okf);
}

// Round 7
// 487.046 us; speedup vs baseline: 2.9400x; 1.0335x over previous
//
#include <hip/hip_runtime.h>
#include <cstdint>

#define B 16
#define N 262144
#define PRE 6000
#define KOUT 1000
#define MW 94            // 64-bit mask words per row (6016 bits >= 6000)
#define CW 40            // fast-path column words: rows 0..2559 (see k_scan_fast)
#define NBIN 2049
#define IMGMAX 511.0f
#define NMS_TH 0.7f

typedef unsigned int u32;
typedef unsigned long long u64;

// ---- workspace layout (bytes) ----
// mask is COLUMN-MAJOR: mask[img][cw][row], cw=0..93, row=0..5999.
#define OFF_MASK  0ull                    // 16*94*6000*8         = 72,192,000
#define OFF_SEL   72192000ull             // 16*16384*8           =  2,097,152
#define OFF_BOX   74289152ull             // 16*6016*16           =  1,540,096
#define OFF_VAL   75829248ull             // 16*96*8              =     12,288
#define OFF_HIST  75841536ull             // 16*2052*4            =    131,328
#define OFF_T     75972864ull             // 16*4                 =         64
#define OFF_CNT   75972928ull             // 16*2*4               =        128
#define OFF_FLAG  75973056ull             // 16*4                 =         64
#define WS_NEED   75973120ull
// memset region each call: OFF_VAL .. end = 143,872 bytes

// Box decode — mirrors reference op order; contraction off so we don't fuse
// mul+add where XLA doesn't (keep/valid comparisons must match bit-for-bit).
__device__ __forceinline__ void box_from(const float4 a, const float4 d,
    float& x1, float& y1, float& x2, float& y2, bool& valid) {
#pragma clang fp contract(off)
  float w  = a.z - a.x;
  float h  = a.w - a.y;
  float cx = a.x + 0.5f * w;
  float cy = a.y + 0.5f * h;
  cx = cx + d.x * w;
  cy = cy + d.y * h;
  w = w * expf(d.z);
  h = h * expf(d.w);
  x1 = cx - 0.5f * w;
  y1 = cy - 0.5f * h;
  x2 = cx + 0.5f * w;
  y2 = cy + 0.5f * h;
  x1 = fminf(fmaxf(x1, 0.0f), IMGMAX);
  y1 = fminf(fmaxf(y1, 0.0f), IMGMAX);
  x2 = fminf(fmaxf(x2, 0.0f), IMGMAX);
  y2 = fminf(fmaxf(y2, 0.0f), IMGMAX);
  valid = ((x2 - x1) >= 16.0f) && ((y2 - y1) >= 16.0f);
}

// IoU > 0.7 decision, bit-exact vs IEEE div: fast path uses v_rcp (<=2ulp);
// only lanes with |qa-0.7| <= 1e-4 (P ~ 1e-5) take the exact-div path under
// exec mask. rcp error near 0.7 is ~2e-7 — 500x inside the guard.
__device__ __forceinline__ bool iou_gt(float inter, float denom) {
  float qa = inter * __builtin_amdgcn_rcpf(denom);
  if (__builtin_expect(fabsf(qa - NMS_TH) <= 1e-4f, 0))
    return (inter / denom) > NMS_TH;
  return qa > NMS_TH;
}

// K1: per-image score histogram, grid (256, B) — full-machine decode.
// LDS histogram + nonzero-guarded no-return atomic merge.
// Block x==0 also zeroes boxes rows 6000..6015 (read by k_mask as columns
// whose bits are never consulted; zeroing keeps them deterministic).
__global__ void k_hist(const float4* __restrict__ anch, const float2* __restrict__ probs,
                       const float4* __restrict__ delt, u32* __restrict__ hist,
                       float4* __restrict__ boxes) {
  __shared__ u32 sh[NBIN];
  int t = threadIdx.x;
  int img = blockIdx.y;
  if (blockIdx.x == 0 && t < 16)
    boxes[(size_t)img * 6016 + 6000 + t] = make_float4(0.f, 0.f, 0.f, 0.f);
  for (int p = t; p < NBIN; p += 256) sh[p] = 0;
  __syncthreads();
  int base = blockIdx.x * 1024;
  for (int r = 0; r < 4; r++) {
    int i = base + r * 256 + t;
    float4 a = anch[i];
    float4 d = delt[(size_t)img * N + i];
    float s = probs[(size_t)img * N + i].y;
    float x1, y1, x2, y2; bool valid;
    box_from(a, d, x1, y1, x2, y2, valid);
    int bin = valid ? (1 + min(2047, (int)(s * 2048.0f))) : 0;
    atomicAdd(&sh[bin], 1u);
  }
  __syncthreads();
  for (int p = t; p < NBIN; p += 256)
    if (sh[p]) atomicAdd(&hist[img * 2052 + p], sh[p]);
}

// K2: T = max bin b (over valid bins 1..2048) with suffix_count(b) >= PRE.
__global__ void k_thresh(const u32* __restrict__ hist, int* __restrict__ Tarr) {
  int img = blockIdx.x;
  int l = threadIdx.x;                       // 64 lanes
  const u32* hb = hist + img * 2052;
  u32 v[32];
  u32 csum = 0;
#pragma unroll
  for (int k = 0; k < 32; k++) { v[k] = hb[l * 32 + 1 + k]; csum += v[k]; }
  u32 sfx = csum;                            // suffix-inclusive over lanes >= l
  for (int off = 1; off < 64; off <<= 1) {
    u32 tv = __shfl_down(sfx, off);
    if (l + off < 64) sfx += tv;
  }
  u32 excl = sfx - csum;
  if (l == 0 && sfx < PRE) Tarr[img] = 0;    // degenerate: < PRE valid boxes
  if (excl < PRE && sfx >= PRE) {            // exactly one lane
    u32 acc = excl; int T = 0;
#pragma unroll
    for (int k = 31; k >= 0; k--) { acc += v[k]; if (acc >= PRE) { T = l * 32 + 1 + k; break; } }
    Tarr[img] = T;
  }
}

// K3: compact candidates. Block-local LDS aggregation; ONE global atomic per
// block per list. sel order nondeterministic; unique keys + exact k_rank ->
// deterministic final output.
__global__ void k_compact(const float4* __restrict__ anch, const float2* __restrict__ probs,
                          const float4* __restrict__ delt, const int* __restrict__ Tarr,
                          u64* __restrict__ sel, u32* __restrict__ cnt) {
  __shared__ u64 buf[1024];
  __shared__ u32 c0, c1, base0, base1;
  int t = threadIdx.x, img = blockIdx.y;
  if (t == 0) { c0 = 0; c1 = 0; }
  __syncthreads();
  int T = Tarr[img];
  int base = blockIdx.x * 1024;
  for (int r = 0; r < 4; r++) {
    int i = base + r * 256 + t;
    float4 a = anch[i];
    float4 d = delt[(size_t)img * N + i];
    float s = probs[(size_t)img * N + i].y;
    float x1, y1, x2, y2; bool valid;
    box_from(a, d, x1, y1, x2, y2, valid);
    int bin = valid ? (1 + min(2047, (int)(s * 2048.0f))) : 0;
    if (bin >= T) {
      u32 u = valid ? (__float_as_uint(s) | 0x80000000u) : 0u;
      u64 key = ((u64)u << 32) | (u64)(0xFFFFFFFFu - (u32)i);
      if (bin > T) { u32 p = atomicAdd(&c0, 1u); buf[p] = key; }
      else         { u32 p = atomicAdd(&c1, 1u); buf[1023 - p] = key; }
    }
  }
  __syncthreads();
  if (t == 0 && c0) base0 = atomicAdd(&cnt[img * 2 + 0], c0);
  if (t == 1 && c1) base1 = atomicAdd(&cnt[img * 2 + 1], c1);
  __syncthreads();
  u64* sb = sel + (size_t)img * 16384;
  for (u32 p = t; p < c0; p += 256) {
    u32 dpos = base0 + p;
    if (dpos < 8192u) sb[dpos] = buf[p];
  }
  for (u32 p = t; p < c1; p += 256) {
    u32 dpos = base1 + p;
    if (dpos < 8192u) sb[8192 + dpos] = buf[1023 - p];
  }
}

// K4: exact pairwise RANK replaces the bitonic sort (which ran 16 blocks on
// 16 of 256 CUs: 2.8% occupancy, 144us of barrier+LDS latency). Keys unique
// -> rank(i) = #{j: key_j > key_i} is an exact permutation; sorted[rank]=key
// IS the descending stable sort. ~37M u64-compares/img over the full machine;
// j-tile staged in LDS, read BROADCAST (all lanes same word — conflict-free).
// Threads with rank < PRE decode their box and scatter; valid bit -> validw
// (pre-zeroed) via fire-and-forget atomicOr, ~64 per word.
__global__ void k_rank(const u64* __restrict__ sel, const u32* __restrict__ cnt,
                       const float4* __restrict__ anch, const float4* __restrict__ delt,
                       float4* __restrict__ boxes, u64* __restrict__ validw) {
  __shared__ u64 sh[1024];
  int t = threadIdx.x, img = blockIdx.y;
  u32 e0 = min(cnt[img * 2 + 0], 8192u);
  u32 e1 = min(cnt[img * 2 + 1], 8192u);
  u32 M = e0 + e1;
  if (blockIdx.x * 256u >= M) return;        // empty block, no syncthreads run
  const u64* sb = sel + (size_t)img * 16384;
  u32 ci = blockIdx.x * 256u + (u32)t;
  bool have = ci < M;
  u64 mykey = 0ull;
  if (have) mykey = (ci < e0) ? sb[ci] : sb[8192 + (ci - e0)];
  u32 rank = 0;
  for (u32 jb = 0; jb < M; jb += 1024) {
    u32 tl = min(1024u, M - jb);
    __syncthreads();
    for (u32 p = t; p < tl; p += 256) {
      u32 j = jb + p;
      sh[p] = (j < e0) ? sb[j] : sb[8192 + (j - e0)];
    }
    __syncthreads();
    if (have) {
      u32 full = tl & ~3u;
      for (u32 p = 0; p < full; p += 4) {
        rank += (sh[p]     > mykey);
        rank += (sh[p + 1] > mykey);
        rank += (sh[p + 2] > mykey);
        rank += (sh[p + 3] > mykey);
      }
      for (u32 p = full; p < tl; p++) rank += (sh[p] > mykey);
    }
  }
  if (have && rank < PRE) {
    u32 u  = (u32)(mykey >> 32);
    u32 gi = 0xFFFFFFFFu - (u32)(mykey & 0xFFFFFFFFull);
    float4 a = anch[gi];
    float4 d = delt[(size_t)img * N + gi];
    float x1, y1, x2, y2; bool valid;
    box_from(a, d, x1, y1, x2, y2, valid);
    boxes[(size_t)img * 6016 + rank] = make_float4(x1, y1, x2, y2);
    if (u != 0u)
      atomicOr(&validw[img * 96 + (rank >> 6)], 1ull << (rank & 63));
  }
}

// K5a: IoU suppression bitmask, FAST REGION ONLY: column words 0..CW-1 with
// their upper-triangle row blocks (rows < CW*64). 18% of the full triangle.
// COLUMN-MAJOR store: wave (fixed cb, 64 rows) = one coalesced 512B store.
__global__ void k_mask(const float4* __restrict__ boxes, u64* __restrict__ mask) {
  __shared__ float4 cbox[4][64];
  __shared__ float  carea[4][64];
  int t = threadIdx.x;
  int rl = t & 63, g = t >> 6;
  int rb = blockIdx.x, img = blockIdx.y;     // rb in [0, CW)
  const float4* bb = boxes + (size_t)img * 6016;
  int r = rb * 64 + rl;
  float4 rx = bb[r];
  float ra = (rx.z - rx.x) * (rx.w - rx.y);
  u64* mimg = mask + (size_t)img * 94 * 6000;
  int jmax = (CW - rb + 3) >> 2;
  for (int j = 0; j < jmax; j++) {
    int cb = rb + g + 4 * j;
    bool act = cb < CW;
    __syncthreads();
    if (act) {
      float4 c = bb[cb * 64 + rl];
      cbox[g][rl] = c;
      carea[g][rl] = (c.z - c.x) * (c.w - c.y);
    }
    __syncthreads();
    if (act) {
#pragma clang fp contract(off)
      u64 bits = 0ull;
      for (int m = 0; m < 64; m++) {
        float4 cx = cbox[g][m];
        float xx1 = fmaxf(rx.x, cx.x);
        float yy1 = fmaxf(rx.y, cx.y);
        float xx2 = fminf(rx.z, cx.z);
        float yy2 = fminf(rx.w, cx.w);
        float inter = fmaxf(xx2 - xx1, 0.0f) * fmaxf(yy2 - yy1, 0.0f);
        float denom = ra + carea[g][m] - inter + 1e-9f;
        int c_j = cb * 64 + m;
        if (iou_gt(inter, denom) && c_j != r) bits |= (1ull << m);
      }
      mimg[(size_t)cb * 6000 + r] = bits;
    }
  }
}

// K5b: rescue — remaining triangle (cb >= max(rb,CW)). No-op when the fast
// scan succeeded for this image (okf[img]==1, the expected case).
__global__ void k_mask_rest(const float4* __restrict__ boxes, u64* __restrict__ mask,
                            const u32* __restrict__ okf) {
  int rb = blockIdx.x, img = blockIdx.y;
  if (okf[img]) return;
  __shared__ float4 cbox[4][64];
  __shared__ float  carea[4][64];
  int t = threadIdx.x;
  int rl = t & 63, g = t >> 6;
  const float4* bb = boxes + (size_t)img * 6016;
  int r = rb * 64 + rl;
  float4 rx = bb[r];
  float ra = (rx.z - rx.x) * (rx.w - rx.y);
  u64* mimg = mask + (size_t)img * 94 * 6000;
  int cb0 = rb > CW ? rb : CW;
  int jmax = (94 - cb0 + 3) >> 2;
  for (int j = 0; j < jmax; j++) {
    int cb = cb0 + g + 4 * j;
    bool act = cb < 94;
    __syncthreads();
    if (act) {
      float4 c = bb[cb * 64 + rl];
      cbox[g][rl] = c;
      carea[g][rl] = (c.z - c.x) * (c.w - c.y);
    }
    __syncthreads();
    if (act) {
#pragma clang fp contract(off)
      u64 bits = 0ull;
      for (int m = 0; m < 64; m++) {
        float4 cx = cbox[g][m];
        float xx1 = fmaxf(rx.x, cx.x);
        float yy1 = fmaxf(rx.y, cx.y);
        float xx2 = fminf(rx.z, cx.z);
        float yy2 = fminf(rx.w, cx.w);
        float inter = fmaxf(xx2 - xx1, 0.0f) * fmaxf(yy2 - yy1, 0.0f);
        float denom = ra + carea[g][m] - inter + 1e-9f;
        int c_j = cb * 64 + m;
        if (iou_gt(inter, denom) && c_j != r) bits |= (1ull << m);
      }
      if (r < PRE) mimg[(size_t)cb * 6000 + r] = bits;
    }
  }
}

// K6a: fast greedy scan over rows 0..CW*64-1, one wave per image. Lane l<CW
// owns column word l (16 consecutive u64 per prefetch step — column-major).
// Succeeds iff 1000 keeps found within CW*64 rows; writes okf + output then.
__global__ void k_scan_fast(const u64* __restrict__ mask, const u64* __restrict__ validw,
                            const float4* __restrict__ boxes, float4* __restrict__ out,
                            u32* __restrict__ okf) {
  __shared__ unsigned short kept[KOUT];
  int l = threadIdx.x;
  int img = blockIdx.x;
  const u64* vw = validw + img * 96;
  u64 r0 = ~vw[l];                            // lanes >= CW never consulted (w<CW)
  const u64* c0p = mask + ((size_t)img * 94 + l) * 6000;
  bool ld = (l < CW);

  u64 ca[16], na[16];
#pragma unroll
  for (int k = 0; k < 16; k++) ca[k] = ld ? c0p[k] : 0ull;
  int cnt = 0; bool done = false;
  for (int base = 0; base < CW * 64; base += 16) {
#pragma unroll
    for (int k = 0; k < 16; k++) {
      int rr = base + 16 + k;
      na[k] = (ld && rr < CW * 64) ? c0p[rr] : 0ull;
    }
#pragma unroll
    for (int k = 0; k < 16; k++) {
      if (!done) {
        int i = base + k;
        int w = i >> 6;
        u64 wv = __shfl(r0, w);
        if (!((wv >> (i & 63)) & 1ull)) {
          if (l == 0 && cnt < KOUT) kept[cnt] = (unsigned short)i;
          cnt++;
          r0 |= (l >= w) ? ca[k] : 0ull;      // words < w unwritten junk
          if (cnt >= KOUT) done = true;
        }
      }
    }
    if (done) break;
#pragma unroll
    for (int k = 0; k < 16; k++) ca[k] = na[k];
  }
  if (l == 0) okf[img] = (cnt >= KOUT) ? 1u : 0u;
  __syncthreads();
  if (cnt >= KOUT) {
    for (int p = l; p < KOUT; p += 64)
      out[(size_t)img * KOUT + p] = boxes[(size_t)img * 6016 + kept[p]];
  }
}

// K6b: full-depth rescue scan (94 words, rows 0..5999). No-op when fast
// scan succeeded. Identical semantics to the reference NMS.
__global__ void k_scan_full(const u64* __restrict__ mask, const u64* __restrict__ validw,
                            const float4* __restrict__ boxes, float4* __restrict__ out,
                            const u32* __restrict__ okf) {
  int img = blockIdx.x;
  if (okf[img]) return;
  __shared__ unsigned short kept[KOUT];
  int l = threadIdx.x;
  const u64* vw = validw + img * 96;
  u64 r0 = ~vw[l];
  u64 r1 = (l < MW - 64) ? ~vw[64 + l] : ~0ull;
  const u64* c0p = mask + ((size_t)img * 94 + l) * 6000;
  const u64* c1p = mask + ((size_t)img * 94 + (l < MW - 64 ? 64 + l : 0)) * 6000;

  u64 ca[16], cb[16], na[16], nb2[16];
#pragma unroll
  for (int k = 0; k < 16; k++) {
    ca[k] = c0p[k];
    cb[k] = (l < MW - 64) ? c1p[k] : 0ull;
  }
  int cnt = 0; bool done = false;
  for (int base = 0; base < PRE; base += 16) {
#pragma unroll
    for (int k = 0; k < 16; k++) {
      int rr = base + 16 + k;
      if (rr < PRE) {
        na[k]  = c0p[rr];
        nb2[k] = (l < MW - 64) ? c1p[rr] : 0ull;
      } else { na[k] = 0ull; nb2[k] = 0ull; }
    }
#pragma unroll
    for (int k = 0; k < 16; k++) {
      if (!done) {
        int i = base + k;
        int w = i >> 6;
        u64 wv = (w < 64) ? __shfl(r0, w) : __shfl(r1, w - 64);
        if (!((wv >> (i & 63)) & 1ull)) {
          if (l == 0 && cnt < KOUT) kept[cnt] = (unsigned short)i;
          cnt++;
          r0 |= (l >= w)        ? ca[k] : 0ull;
          r1 |= ((64 + l) >= w) ? cb[k] : 0ull;
          if (cnt >= KOUT) done = true;
        }
      }
    }
    if (done) break;
#pragma unroll
    for (int k = 0; k < 16; k++) { ca[k] = na[k]; cb[k] = nb2[k]; }
  }
  __syncthreads();
  for (int p = l; p < KOUT; p += 64) {
    float4 v = make_float4(0.f, 0.f, 0.f, 0.f);
    if (p < cnt) v = boxes[(size_t)img * 6016 + kept[p]];
    out[(size_t)img * KOUT + p] = v;
  }
}

extern "C" void kernel_launch(void* const* d_in, const int* in_sizes, int n_in,
                              void* d_out, int out_size, void* d_ws, size_t ws_size,
                              hipStream_t stream) {
  const float4* anch  = (const float4*)d_in[0];
  const float2* probs = (const float2*)d_in[1];
  const float4* delt  = (const float4*)d_in[2];
  float4* out = (float4*)d_out;
  char* ws = (char*)d_ws;
  (void)in_sizes; (void)n_in;

  if (ws_size < WS_NEED) {  // not enough scratch: write zeros, bail cleanly
    (void)hipMemsetAsync(d_out, 0, (size_t)out_size * sizeof(float), stream);
    return;
  }

  u64* mask    = (u64*)(ws + OFF_MASK);
  u64* sel     = (u64*)(ws + OFF_SEL);
  float4* bxs  = (float4*)(ws + OFF_BOX);
  u64* validw  = (u64*)(ws + OFF_VAL);
  u32* hist    = (u32*)(ws + OFF_HIST);
  int* Tarr    = (int*)(ws + OFF_T);
  u32* cnt     = (u32*)(ws + OFF_CNT);
  u32* okf     = (u32*)(ws + OFF_FLAG);

  // zero validw + hist + Tarr + cnt + flag every call (contiguous tail)
  (void)hipMemsetAsync(ws + OFF_VAL, 0, 143872, stream);

  dim3 g1(256, B);
  k_hist<<<g1, 256, 0, stream>>>(anch, probs, delt, hist, bxs);
  k_thresh<<<B, 64, 0, stream>>>(hist, Tarr);
  k_compact<<<g1, 256, 0, stream>>>(anch, probs, delt, Tarr, sel, cnt);
  dim3 g4(64, B);
  k_rank<<<g4, 256, 0, stream>>>(sel, cnt, anch, delt, bxs, validw);
  dim3 g5(CW, B);
  k_mask<<<g5, 256, 0, stream>>>(bxs, mask);
  k_scan_fast<<<B, 64, 0, stream>>>(mask, validw, bxs, out, okf);
  dim3 g5b(94, B);
  k_mask_rest<<<g5b, 256, 0, stream>>>(bxs, mask, okf);
  k_scan_full<<<B, 64, 0, stream>>>(mask, validw, bxs, out, okf);
}